// Round 22
// baseline (65.518 us; speedup 1.0000x reference)
//
#include <hip/hip_runtime.h>
#include <hip/hip_fp16.h>

// Problem constants
#define NB   8
#define NC   256
#define HW   56
#define NPX  3136          // 56*56
#define RED  64
#define NG   16
#define GC   16
#define KS   7
#define KK   49
#define PADK 3
#define XPH  62            // padded rows: 3 + 56 + 3
#define XPW  64            // padded row stride (elements)
#define XPSLICE (XPH * XPW)   // 3968 f16 per channel slice
// K2 tiling (r15/r18 geometry)
#define TPX  224           // px tile = 4 full pixel rows
#define NT2  14            // 3136 / 224
#define XT2_CS 644         // xtap ch stride (f16): 10*64+4 -> bank spread
#define WSTR2  232         // wls px stride (f16): 464 B, 16B-multiple

typedef float f32x4 __attribute__((ext_vector_type(4)));
typedef _Float16 h16x4 __attribute__((ext_vector_type(4)));
typedef _Float16 h16x8 __attribute__((ext_vector_type(8)));

// ---------------------------------------------------------------------------
// K0: fused prep (r18 version).  blocks 0..2047: pad+convert x -> xpad f16,
//     XCD-ALIGNED (b = bid&7: batch written by the XCD that later reads it);
//     blocks 2048..2063: w2 -> w2h f16; block 2064: w1 -> w1h f16.
// ---------------------------------------------------------------------------
__global__ __launch_bounds__(256) void prep_kernel(
    const float* __restrict__ x, const float* __restrict__ w1,
    const float* __restrict__ w2, _Float16* __restrict__ xpad,
    _Float16* __restrict__ w1h, _Float16* __restrict__ w2h) {
    int bid = blockIdx.x;
    if (bid < NB * NC) {
        int b = bid & 7, c = bid >> 3;         // XCD-aligned: batch = XCD
        const float* xs = x + ((size_t)b * NC + c) * NPX;
        _Float16* xd = xpad + ((size_t)b * NC + c) * XPSLICE;
#pragma unroll 4
        for (int e = threadIdx.x; e < XPSLICE; e += 256) {
            int row = e >> 6, col = e & 63;
            int h = row - PADK, w = col - PADK;
            float v = (h >= 0 && h < HW && w >= 0 && w < HW) ? xs[h * HW + w] : 0.0f;
            xd[e] = (_Float16)v;
        }
    } else if (bid < NB * NC + NG) {
        int g = bid - NB * NC;
#pragma unroll 4
        for (int e = threadIdx.x; e < 4096; e += 256) {
            int m = e >> 6, k = e & 63;
            float v = (m < KK) ? w2[((size_t)g * KK + m) * RED + k] : 0.0f;
            w2h[(size_t)g * 4096 + e] = (_Float16)v;
        }
    } else {
#pragma unroll 4
        for (int e = threadIdx.x; e < 64 * 256; e += 256)
            w1h[e] = (_Float16)w1[e];
    }
}

// ---------------------------------------------------------------------------
// K1: conv1 via MFMA f16 (r12/r18 version, 1 wave/block).
// Grid 1568 (8b x 196 nt; b = wgid&7 = XCD), 64 thr. Wave: C[64 o][16 px].
// Gathers hit the local XCD L2 (xpad written by same XCD in prep).
// ---------------------------------------------------------------------------
__global__ __launch_bounds__(64) void conv1_kernel(
    const _Float16* __restrict__ xpad, const _Float16* __restrict__ w1h,
    const float* __restrict__ g1, const float* __restrict__ be1,
    const float* __restrict__ mu1, const float* __restrict__ var1,
    _Float16* __restrict__ tT) {
    int lane = threadIdx.x;
    int l15 = lane & 15, l4 = lane >> 4;
    int wgid = blockIdx.x;                 // 1568 = 8 * 196
    int b  = wgid & 7;                     // XCD-local batch
    int nt = wgid >> 3;                    // 0..195
    int px = nt * 16 + l15;
    int h = px / HW, w = px % HW;

    const _Float16* xp = xpad + (size_t)b * NC * XPSLICE
                       + (h + PADK) * XPW + (w + PADK);

    f32x4 acc0 = {0,0,0,0}, acc1 = {0,0,0,0}, acc2 = {0,0,0,0}, acc3 = {0,0,0,0};
#pragma unroll
    for (int kk = 0; kk < 8; ++kk) {
        h16x8 bfr;
#pragma unroll
        for (int i = 0; i < 8; ++i)
            bfr[i] = xp[(size_t)(kk * 32 + l4 * 8 + i) * XPSLICE];
#pragma unroll
        for (int mt = 0; mt < 4; ++mt) {
            const _Float16* ap = w1h + (mt * 16 + l15) * NC + kk * 32 + l4 * 8;
            h16x8 a = *(const h16x8*)ap;
            f32x4 c = (mt == 0) ? acc0 : (mt == 1) ? acc1 : (mt == 2) ? acc2 : acc3;
            c = __builtin_amdgcn_mfma_f32_16x16x32_f16(a, bfr, c, 0, 0, 0);
            if (mt == 0) acc0 = c; else if (mt == 1) acc1 = c;
            else if (mt == 2) acc2 = c; else acc3 = c;
        }
    }

    _Float16* tb = tT + ((size_t)b * NPX + px) * RED;
#pragma unroll
    for (int mt = 0; mt < 4; ++mt) {
        f32x4 a = (mt == 0) ? acc0 : (mt == 1) ? acc1 : (mt == 2) ? acc2 : acc3;
        int o0 = mt * 16 + l4 * 4;
        h16x4 pk;
#pragma unroll
        for (int r = 0; r < 4; ++r) {
            int o = o0 + r;
            float inv = g1[o] * rsqrtf(var1[o] + 1e-5f);
            float v = a[r] * inv + (be1[o] - mu1[o] * inv);
            pk[r] = (_Float16)fmaxf(v, 0.0f);
        }
        *(h16x4*)(tb + o0) = pk;
    }
}

// ---------------------------------------------------------------------------
// K2: fused conv2(MFMA f16) -> involution -> bn2 -> relu (r18 core +
// T5 setprio around the MFMA cluster + f16 cc in phase B -> both-f16
// v_fma_mix, no explicit cvt).
// Tile = 224 px x 1 group. Grid 1792 (XCD-swizzled 8x224), 448 thr = 7 waves.
// ---------------------------------------------------------------------------
__global__ __launch_bounds__(448, 3) void involution_kernel(
    const _Float16* __restrict__ xpad, const _Float16* __restrict__ tT,
    const _Float16* __restrict__ w2h, const float* __restrict__ b2,
    const float* __restrict__ g2, const float* __restrict__ be2,
    const float* __restrict__ mu2, const float* __restrict__ var2,
    float* __restrict__ out) {
    __shared__ __align__(16) _Float16 xtap[GC * XT2_CS];  // 20,608 B
    __shared__ __align__(16) _Float16 wls[KK * WSTR2];    // 22,736 B

    int tid  = threadIdx.x;
    int lane = tid & 63;
    int wv   = __builtin_amdgcn_readfirstlane(tid >> 6);   // 0..6 SGPR
    int wgid = blockIdx.x;                 // 1792 = 8 * 224
    int swz  = (wgid & 7) * 224 + (wgid >> 3);
    int b    = swz / 224;
    int rem  = swz % 224;
    int g    = rem / NT2;                  // 0..15
    int tile = rem % NT2;                  // 0..13
    int px0 = tile * TPX;
    int R0  = tile * 4;                    // first output pixel-row

    const _Float16* xpg = xpad + ((size_t)b * NC + (size_t)g * GC) * XPSLICE;

    // ---- step 1 (T14): issue xtap staging loads (1280 16B-chunks) ----
    h16x8 xr[3];
#pragma unroll
    for (int u = 0; u < 3; ++u) {
        int cid = u * 448 + tid;
        if (cid < 1280) {
            int ch = cid / 80;             // 80 = 10 rows * 8 chunks
            int rm = cid % 80;
            int rr = rm >> 3, c8 = rm & 7;
            xr[u] = *(const h16x8*)(xpg + (size_t)ch * XPSLICE
                                    + (R0 + rr) * XPW + c8 * 8);
        }
    }

    // ---- step 2: phase A MFMA  wgt[49 x 224px] = w2h[49x64r] . tT[px][64r] ----
    {
        int l15 = lane & 15, l4 = lane >> 4;
        const _Float16* wA = w2h + (size_t)g * 4096;
        const float* bg = b2 + (size_t)g * KK;
        h16x8 a0[4], a1[4];
#pragma unroll
        for (int mt = 0; mt < 4; ++mt) {
            const _Float16* ap = wA + (mt * 16 + l15) * 64 + l4 * 8;
            a0[mt] = *(const h16x8*)(ap);
            a1[mt] = *(const h16x8*)(ap + 32);
        }
#pragma unroll
        for (int it = 0; it < 2; ++it) {
            int nt = wv * 2 + it;          // 0..13 (wave-uniform)
            int pxc = px0 + nt * 16 + l15;
            const _Float16* tp = tT + ((size_t)b * NPX + pxc) * RED + l4 * 8;
            h16x8 bfr0 = *(const h16x8*)tp;
            h16x8 bfr1 = *(const h16x8*)(tp + 32);

            f32x4 acc0 = {0,0,0,0}, acc1 = {0,0,0,0},
                  acc2 = {0,0,0,0}, acc3 = {0,0,0,0};
            __builtin_amdgcn_s_setprio(1);         // T5: favor MFMA cluster
#pragma unroll
            for (int mt = 0; mt < 4; ++mt) {
                f32x4 a = (mt == 0) ? acc0 : (mt == 1) ? acc1
                        : (mt == 2) ? acc2 : acc3;
                a = __builtin_amdgcn_mfma_f32_16x16x32_f16(a0[mt], bfr0, a, 0, 0, 0);
                a = __builtin_amdgcn_mfma_f32_16x16x32_f16(a1[mt], bfr1, a, 0, 0, 0);
                if (mt == 0) acc0 = a; else if (mt == 1) acc1 = a;
                else if (mt == 2) acc2 = a; else acc3 = a;
            }
            __builtin_amdgcn_s_setprio(0);
            _Float16* wl = wls + nt * 16 + l15;
#pragma unroll
            for (int mt = 0; mt < 4; ++mt) {
                f32x4 a = (mt == 0) ? acc0 : (mt == 1) ? acc1
                        : (mt == 2) ? acc2 : acc3;
#pragma unroll
                for (int r = 0; r < 4; ++r) {
                    int k = mt * 16 + l4 * 4 + r;
                    if (k < KK) wl[k * WSTR2] = (_Float16)(a[r] + bg[k]);
                }
            }
        }
    }

    // ---- step 3: write staged regs to LDS, ONE barrier ----
#pragma unroll
    for (int u = 0; u < 3; ++u) {
        int cid = u * 448 + tid;
        if (cid < 1280) {
            int ch = cid / 80;
            int rm = cid % 80;
            int rr = rm >> 3, c8 = rm & 7;
            *(h16x8*)&xtap[ch * XT2_CS + rr * 64 + c8 * 8] = xr[u];
        }
    }
    __syncthreads();

    // ---- step 4: phase B, thread = (octet, ch): 8 px x 1 ch ----
    int octet = tid >> 4;                  // 0..27
    int ch    = tid & 15;                  // 0..15
    int lin   = octet * 8;                 // 0..216
    int lh    = lin / 56;                  // 0..3
    int w0    = lin % 56;                  // multiple of 8

    const _Float16* xb0 = xtap + ch * XT2_CS + lh * 64 + w0;
    float acc[8];
#pragma unroll
    for (int p = 0; p < 8; ++p) acc[p] = 0.0f;

#pragma unroll
    for (int i = 0; i < KS; ++i) {
        h16x8 t0 = *(const h16x8*)(xb0 + i * 64);       // cols w0..w0+7
        h16x8 t1 = *(const h16x8*)(xb0 + i * 64 + 8);   // cols w0+8..w0+15
        _Float16 cc[16];                   // keep f16: both-f16 v_fma_mix
#pragma unroll
        for (int p = 0; p < 8; ++p) { cc[p] = t0[p]; cc[8 + p] = t1[p]; }
#pragma unroll
        for (int j = 0; j < KS; ++j) {
            h16x8 wq = *(const h16x8*)&wls[(i * KS + j) * WSTR2 + lin];
#pragma unroll
            for (int p = 0; p < 8; ++p)
                acc[p] = fmaf((float)wq[p], (float)cc[j + p], acc[p]);
        }
    }

    int c_ = g * GC + ch;
    float inv = g2[c_] * rsqrtf(var2[c_] + 1e-5f);
    float off = be2[c_] - mu2[c_] * inv;
    float* op = out + ((size_t)b * NC + c_) * NPX + px0 + lin;
    f32x4 o0, o1;
#pragma unroll
    for (int p = 0; p < 4; ++p) {
        o0[p] = fmaxf(acc[p] * inv + off, 0.0f);
        o1[p] = fmaxf(acc[4 + p] * inv + off, 0.0f);
    }
    *(f32x4*)(op)     = o0;
    *(f32x4*)(op + 4) = o1;
}

// ---------------------------------------------------------------------------
extern "C" void kernel_launch(void* const* d_in, const int* in_sizes, int n_in,
                              void* d_out, int out_size, void* d_ws, size_t ws_size,
                              hipStream_t stream) {
    const float* x    = (const float*)d_in[0];
    const float* w1   = (const float*)d_in[1];
    const float* g1   = (const float*)d_in[2];
    const float* be1  = (const float*)d_in[3];
    const float* mu1  = (const float*)d_in[4];
    const float* var1 = (const float*)d_in[5];
    const float* w2   = (const float*)d_in[6];
    const float* b2   = (const float*)d_in[7];
    const float* g2   = (const float*)d_in[8];
    const float* be2  = (const float*)d_in[9];
    const float* mu2  = (const float*)d_in[10];
    const float* var2 = (const float*)d_in[11];
    float* outp = (float*)d_out;

    // ws: xpad f16 16.3MB | tT f16 3.2MB | w2h 128KB | w1h 32KB
    _Float16* xpad = (_Float16*)d_ws;
    _Float16* tT   = xpad + (size_t)NB * NC * XPSLICE;
    _Float16* w2h  = tT + (size_t)NB * NPX * RED;
    _Float16* w1h  = w2h + (size_t)NG * 4096;

    prep_kernel<<<NB * NC + NG + 1, 256, 0, stream>>>(x, w1, w2, xpad, w1h, w2h);
    conv1_kernel<<<1568, 64, 0, stream>>>(xpad, w1h, g1, be1, mu1, var1, tT);
    involution_kernel<<<1792, 448, 0, stream>>>(
        xpad, tT, w2h, b2, g2, be2, mu2, var2, outp);
}

// Round 23
// 63.885 us; speedup vs baseline: 1.0256x; 1.0256x over previous
//
#include <hip/hip_runtime.h>
#include <hip/hip_fp16.h>

// Problem constants
#define NB   8
#define NC   256
#define HW   56
#define NPX  3136          // 56*56
#define RED  64
#define NG   16
#define GC   16
#define KS   7
#define KK   49
#define PADK 3
#define XPH  62            // padded rows: 3 + 56 + 3
#define XPW  64            // padded row stride (elements)
#define XPSLICE (XPH * XPW)   // 3968 f16 per channel slice
// K2 tiling
#define TPX  224           // px tile = 4 full pixel rows
#define NT2  14            // 3136 / 224
#define XT2_CS 644         // xtap ch stride (f16): 10*64+4 -> bank spread
#define WSTR2  232         // wls px stride (f16): 464 B, 16B-multiple

typedef float f32x4 __attribute__((ext_vector_type(4)));
typedef _Float16 h16x4 __attribute__((ext_vector_type(4)));
typedef _Float16 h16x8 __attribute__((ext_vector_type(8)));

// ---------------------------------------------------------------------------
// K0: fused prep.  blocks 0..2047: pad+convert x -> xpad f16, XCD-ALIGNED
//     (b = bid&7: batch written by the XCD that later reads it in conv1/K2);
//     blocks 2048..2063: w2 -> w2h f16; block 2064: w1 -> w1h f16.
// ---------------------------------------------------------------------------
__global__ __launch_bounds__(256) void prep_kernel(
    const float* __restrict__ x, const float* __restrict__ w1,
    const float* __restrict__ w2, _Float16* __restrict__ xpad,
    _Float16* __restrict__ w1h, _Float16* __restrict__ w2h) {
    int bid = blockIdx.x;
    if (bid < NB * NC) {
        int b = bid & 7, c = bid >> 3;         // XCD-aligned: batch = XCD
        const float* xs = x + ((size_t)b * NC + c) * NPX;
        _Float16* xd = xpad + ((size_t)b * NC + c) * XPSLICE;
#pragma unroll 4
        for (int e = threadIdx.x; e < XPSLICE; e += 256) {
            int row = e >> 6, col = e & 63;
            int h = row - PADK, w = col - PADK;
            float v = (h >= 0 && h < HW && w >= 0 && w < HW) ? xs[h * HW + w] : 0.0f;
            xd[e] = (_Float16)v;
        }
    } else if (bid < NB * NC + NG) {
        int g = bid - NB * NC;
#pragma unroll 4
        for (int e = threadIdx.x; e < 4096; e += 256) {
            int m = e >> 6, k = e & 63;
            float v = (m < KK) ? w2[((size_t)g * KK + m) * RED + k] : 0.0f;
            w2h[(size_t)g * 4096 + e] = (_Float16)v;
        }
    } else {
#pragma unroll 4
        for (int e = threadIdx.x; e < 64 * 256; e += 256)
            w1h[e] = (_Float16)w1[e];
    }
}

// ---------------------------------------------------------------------------
// K1: conv1 via MFMA f16 (1 wave/block).
// Grid 1568 (8b x 196 nt; b = wgid&7 = XCD), 64 thr. Wave: C[64 o][16 px]:
// 8 k-steps x 4 m-tiles of mfma_16x16x32_f16. B = xpad gathers (local-XCD
// L2 hits), A = w1h b128 (L1-hot). Epilogue bn1+relu -> f16 tT[b][px][o].
// ---------------------------------------------------------------------------
__global__ __launch_bounds__(64) void conv1_kernel(
    const _Float16* __restrict__ xpad, const _Float16* __restrict__ w1h,
    const float* __restrict__ g1, const float* __restrict__ be1,
    const float* __restrict__ mu1, const float* __restrict__ var1,
    _Float16* __restrict__ tT) {
    int lane = threadIdx.x;
    int l15 = lane & 15, l4 = lane >> 4;
    int wgid = blockIdx.x;                 // 1568 = 8 * 196
    int b  = wgid & 7;                     // XCD-local batch
    int nt = wgid >> 3;                    // 0..195
    int px = nt * 16 + l15;
    int h = px / HW, w = px % HW;

    const _Float16* xp = xpad + (size_t)b * NC * XPSLICE
                       + (h + PADK) * XPW + (w + PADK);

    f32x4 acc0 = {0,0,0,0}, acc1 = {0,0,0,0}, acc2 = {0,0,0,0}, acc3 = {0,0,0,0};
#pragma unroll
    for (int kk = 0; kk < 8; ++kk) {
        h16x8 bfr;
#pragma unroll
        for (int i = 0; i < 8; ++i)
            bfr[i] = xp[(size_t)(kk * 32 + l4 * 8 + i) * XPSLICE];
#pragma unroll
        for (int mt = 0; mt < 4; ++mt) {
            const _Float16* ap = w1h + (mt * 16 + l15) * NC + kk * 32 + l4 * 8;
            h16x8 a = *(const h16x8*)ap;
            f32x4 c = (mt == 0) ? acc0 : (mt == 1) ? acc1 : (mt == 2) ? acc2 : acc3;
            c = __builtin_amdgcn_mfma_f32_16x16x32_f16(a, bfr, c, 0, 0, 0);
            if (mt == 0) acc0 = c; else if (mt == 1) acc1 = c;
            else if (mt == 2) acc2 = c; else acc3 = c;
        }
    }

    _Float16* tb = tT + ((size_t)b * NPX + px) * RED;
#pragma unroll
    for (int mt = 0; mt < 4; ++mt) {
        f32x4 a = (mt == 0) ? acc0 : (mt == 1) ? acc1 : (mt == 2) ? acc2 : acc3;
        int o0 = mt * 16 + l4 * 4;
        h16x4 pk;
#pragma unroll
        for (int r = 0; r < 4; ++r) {
            int o = o0 + r;
            float inv = g1[o] * rsqrtf(var1[o] + 1e-5f);
            float v = a[r] * inv + (be1[o] - mu1[o] * inv);
            pk[r] = (_Float16)fmaxf(v, 0.0f);
        }
        *(h16x4*)(tb + o0) = pk;
    }
}

// ---------------------------------------------------------------------------
// K2: fused conv2(MFMA f16) -> involution -> bn2 -> relu (r18 verbatim —
// the converged configuration after 21 structural variants).
// Tile = 224 px (4 full rows) x 1 group. Grid 1792 (XCD-swizzled 8x224),
// block 448 = 7 waves. LDS: xtap (20.6 KB) + wls [49][232] (22.7 KB).
// ---------------------------------------------------------------------------
__global__ __launch_bounds__(448, 3) void involution_kernel(
    const _Float16* __restrict__ xpad, const _Float16* __restrict__ tT,
    const _Float16* __restrict__ w2h, const float* __restrict__ b2,
    const float* __restrict__ g2, const float* __restrict__ be2,
    const float* __restrict__ mu2, const float* __restrict__ var2,
    float* __restrict__ out) {
    __shared__ __align__(16) _Float16 xtap[GC * XT2_CS];  // 20,608 B
    __shared__ __align__(16) _Float16 wls[KK * WSTR2];    // 22,736 B

    int tid  = threadIdx.x;
    int lane = tid & 63;
    int wv   = __builtin_amdgcn_readfirstlane(tid >> 6);   // 0..6 SGPR
    int wgid = blockIdx.x;                 // 1792 = 8 * 224
    int swz  = (wgid & 7) * 224 + (wgid >> 3);
    int b    = swz / 224;
    int rem  = swz % 224;
    int g    = rem / NT2;                  // 0..15
    int tile = rem % NT2;                  // 0..13
    int px0 = tile * TPX;
    int R0  = tile * 4;                    // first output pixel-row

    const _Float16* xpg = xpad + ((size_t)b * NC + (size_t)g * GC) * XPSLICE;

    // ---- step 1 (T14): issue xtap staging loads (1280 16B-chunks) ----
    h16x8 xr[3];
#pragma unroll
    for (int u = 0; u < 3; ++u) {
        int cid = u * 448 + tid;
        if (cid < 1280) {
            int ch = cid / 80;             // 80 = 10 rows * 8 chunks
            int rm = cid % 80;
            int rr = rm >> 3, c8 = rm & 7;
            xr[u] = *(const h16x8*)(xpg + (size_t)ch * XPSLICE
                                    + (R0 + rr) * XPW + c8 * 8);
        }
    }

    // ---- step 2: phase A MFMA  wgt[49 x 224px] = w2h[49x64r] . tT[px][64r] ----
    {
        int l15 = lane & 15, l4 = lane >> 4;
        const _Float16* wA = w2h + (size_t)g * 4096;
        const float* bg = b2 + (size_t)g * KK;
        h16x8 a0[4], a1[4];
#pragma unroll
        for (int mt = 0; mt < 4; ++mt) {
            const _Float16* ap = wA + (mt * 16 + l15) * 64 + l4 * 8;
            a0[mt] = *(const h16x8*)(ap);
            a1[mt] = *(const h16x8*)(ap + 32);
        }
#pragma unroll
        for (int it = 0; it < 2; ++it) {
            int nt = wv * 2 + it;          // 0..13 (wave-uniform)
            int pxc = px0 + nt * 16 + l15;
            const _Float16* tp = tT + ((size_t)b * NPX + pxc) * RED + l4 * 8;
            h16x8 bfr0 = *(const h16x8*)tp;
            h16x8 bfr1 = *(const h16x8*)(tp + 32);

            f32x4 acc0 = {0,0,0,0}, acc1 = {0,0,0,0},
                  acc2 = {0,0,0,0}, acc3 = {0,0,0,0};
#pragma unroll
            for (int mt = 0; mt < 4; ++mt) {
                f32x4 a = (mt == 0) ? acc0 : (mt == 1) ? acc1
                        : (mt == 2) ? acc2 : acc3;
                a = __builtin_amdgcn_mfma_f32_16x16x32_f16(a0[mt], bfr0, a, 0, 0, 0);
                a = __builtin_amdgcn_mfma_f32_16x16x32_f16(a1[mt], bfr1, a, 0, 0, 0);
                if (mt == 0) acc0 = a; else if (mt == 1) acc1 = a;
                else if (mt == 2) acc2 = a; else acc3 = a;
            }
            _Float16* wl = wls + nt * 16 + l15;
#pragma unroll
            for (int mt = 0; mt < 4; ++mt) {
                f32x4 a = (mt == 0) ? acc0 : (mt == 1) ? acc1
                        : (mt == 2) ? acc2 : acc3;
#pragma unroll
                for (int r = 0; r < 4; ++r) {
                    int k = mt * 16 + l4 * 4 + r;
                    if (k < KK) wl[k * WSTR2] = (_Float16)(a[r] + bg[k]);
                }
            }
        }
    }

    // ---- step 3: write staged regs to LDS, ONE barrier ----
#pragma unroll
    for (int u = 0; u < 3; ++u) {
        int cid = u * 448 + tid;
        if (cid < 1280) {
            int ch = cid / 80;
            int rm = cid % 80;
            int rr = rm >> 3, c8 = rm & 7;
            *(h16x8*)&xtap[ch * XT2_CS + rr * 64 + c8 * 8] = xr[u];
        }
    }
    __syncthreads();

    // ---- step 4: phase B, thread = (octet, ch): 8 px x 1 ch ----
    int octet = tid >> 4;                  // 0..27
    int ch    = tid & 15;                  // 0..15
    int lin   = octet * 8;                 // 0..216
    int lh    = lin / 56;                  // 0..3
    int w0    = lin % 56;                  // multiple of 8

    const _Float16* xb0 = xtap + ch * XT2_CS + lh * 64 + w0;
    float acc[8];
#pragma unroll
    for (int p = 0; p < 8; ++p) acc[p] = 0.0f;

#pragma unroll
    for (int i = 0; i < KS; ++i) {
        h16x8 t0 = *(const h16x8*)(xb0 + i * 64);       // cols w0..w0+7
        h16x8 t1 = *(const h16x8*)(xb0 + i * 64 + 8);   // cols w0+8..w0+15
        float cc[16];
#pragma unroll
        for (int p = 0; p < 8; ++p) { cc[p] = (float)t0[p]; cc[8 + p] = (float)t1[p]; }
#pragma unroll
        for (int j = 0; j < KS; ++j) {
            h16x8 wq = *(const h16x8*)&wls[(i * KS + j) * WSTR2 + lin];
#pragma unroll
            for (int p = 0; p < 8; ++p)
                acc[p] = fmaf((float)wq[p], cc[j + p], acc[p]);
        }
    }

    int c_ = g * GC + ch;
    float inv = g2[c_] * rsqrtf(var2[c_] + 1e-5f);
    float off = be2[c_] - mu2[c_] * inv;
    float* op = out + ((size_t)b * NC + c_) * NPX + px0 + lin;
    f32x4 o0, o1;
#pragma unroll
    for (int p = 0; p < 4; ++p) {
        o0[p] = fmaxf(acc[p] * inv + off, 0.0f);
        o1[p] = fmaxf(acc[4 + p] * inv + off, 0.0f);
    }
    *(f32x4*)(op)     = o0;
    *(f32x4*)(op + 4) = o1;
}

// ---------------------------------------------------------------------------
extern "C" void kernel_launch(void* const* d_in, const int* in_sizes, int n_in,
                              void* d_out, int out_size, void* d_ws, size_t ws_size,
                              hipStream_t stream) {
    const float* x    = (const float*)d_in[0];
    const float* w1   = (const float*)d_in[1];
    const float* g1   = (const float*)d_in[2];
    const float* be1  = (const float*)d_in[3];
    const float* mu1  = (const float*)d_in[4];
    const float* var1 = (const float*)d_in[5];
    const float* w2   = (const float*)d_in[6];
    const float* b2   = (const float*)d_in[7];
    const float* g2   = (const float*)d_in[8];
    const float* be2  = (const float*)d_in[9];
    const float* mu2  = (const float*)d_in[10];
    const float* var2 = (const float*)d_in[11];
    float* outp = (float*)d_out;

    // ws: xpad f16 16.3MB | tT f16 3.2MB | w2h 128KB | w1h 32KB
    _Float16* xpad = (_Float16*)d_ws;
    _Float16* tT   = xpad + (size_t)NB * NC * XPSLICE;
    _Float16* w2h  = tT + (size_t)NB * NPX * RED;
    _Float16* w1h  = w2h + (size_t)NG * 4096;

    prep_kernel<<<NB * NC + NG + 1, 256, 0, stream>>>(x, w1, w2, xpad, w1h, w2h);
    conv1_kernel<<<1568, 64, 0, stream>>>(xpad, w1h, g1, be1, mu1, var1, tT);
    involution_kernel<<<1792, 448, 0, stream>>>(
        xpad, tT, w2h, b2, g2, be2, mu2, var2, outp);
}